// Round 4
// baseline (1252.714 us; speedup 1.0000x reference)
//
#include <hip/hip_runtime.h>

#define TT 512

typedef _Float16 f16;
typedef _Float16 f16x4 __attribute__((ext_vector_type(4)));
typedef _Float16 f16x8 __attribute__((ext_vector_type(8)));
typedef float    f32x4 __attribute__((ext_vector_type(4)));

#define MFMA(A, B, C) __builtin_amdgcn_mfma_f32_16x16x32_f16((A), (B), (C), 0, 0, 0)

#define LOG2E  1.44269504f
#define LOG2E2 2.88539008f

__device__ __forceinline__ float exp2_(float x){
#if __has_builtin(__builtin_amdgcn_exp2f)
    return __builtin_amdgcn_exp2f(x);
#else
    return exp2f(x);
#endif
}
__device__ __forceinline__ float rcp_(float x){
#if __has_builtin(__builtin_amdgcn_rcpf)
    return __builtin_amdgcn_rcpf(x);
#else
    return 1.0f/x;
#endif
}
__device__ __forceinline__ f16x8 ldw8s(const float* p, float s){
    f16x8 r;
    #pragma unroll
    for (int i = 0; i < 8; ++i) r[i] = (f16)(p[i]*s);
    return r;
}

// Gate pre-scaling: i/f/o rows by LOG2E, g rows by LOG2E2 (folded into W+b).
// Shared-rcp activation: sig(a)*tanh(b) = (1-Eb)/((1+Ea)(1+Eb)).
// 8 trans per (unit,batch) pair: Ei,Ef,Eg,Eo,Ec exp2 + 3 rcp.
__device__ __forceinline__ void act4(const f32x4& zi, const f32x4& zf,
                                     const f32x4& zg, const f32x4& zo,
                                     float* c, f16x4& hn){
    #pragma unroll
    for (int j = 0; j < 4; ++j){
        float Ei = exp2_(-zi[j]);
        float Ef = exp2_(-zf[j]);
        float Eg = exp2_(-zg[j]);
        float Eo = exp2_(-zo[j]);
        float ig = (1.0f - Eg) * rcp_((1.0f + Ei)*(1.0f + Eg));   // i*g
        float f_ = rcp_(1.0f + Ef);                                // f
        c[j] = fmaf(f_, c[j], ig);
        float Ec = exp2_(-(LOG2E2*c[j]));
        float h_ = (1.0f - Ec) * rcp_((1.0f + Eo)*(1.0f + Ec));   // o*tanh(c)
        hn[j] = (f16)h_;
    }
}

// 64 blocks x 896 threads (14 waves), 16 batch per block. Pipelined roles:
//   waves 0-3 : L1 @ t=p     waves 4-7 : L2 @ t=p-1   waves 8-11: L3 @ t=p-2
//   wave 12,13: FC tile 0/1 @ t=p-3;  wave 12 stores out @ t=p-4 (x4 batched)
// One __syncthreads per phase; no global loads inside the loop.
// D layout (16x16x32): col(batch)=lane&15, row=4*(lane>>4)+j (R1-verified).
__global__ __launch_bounds__(896, 1) void lstm3_pipe2(
    const float* __restrict__ x,
    const float* __restrict__ w_ih1, const float* __restrict__ w_hh1, const float* __restrict__ b1,
    const float* __restrict__ w_ih2, const float* __restrict__ w_hh2, const float* __restrict__ b2,
    const float* __restrict__ w_ih3, const float* __restrict__ w_hh3, const float* __restrict__ b3,
    const float* __restrict__ fc1_w, const float* __restrict__ fc1_b,
    const float* __restrict__ fc2_w, const float* __restrict__ fc2_b,
    float* __restrict__ out)
{
    __shared__ __align__(16) unsigned char hraw[3*2*2048];  // [layer][parity][16b][64u] f16 swizzled
    __shared__ float x_lds[TT*17];                          // [t][batch] +pad
    __shared__ float s_fc[2][2][16];                        // [fc tile][parity][batch]

    const int tid = threadIdx.x;
    const int wid = tid >> 6;
    const int l   = tid & 63;
    const int q   = l >> 4;
    const int bb  = l & 15;
    const int b0  = blockIdx.x * 16;
    const int role = wid >> 2;          // 0,1,2 = L1,L2,L3 ; 3 = FC
    const int uq   = wid & 3;

    // stage x transposed (coalesced read, conflict-free write)
    for (int i = tid; i < 16*TT; i += 896){
        int b = i >> 9, t = i & (TT-1);
        x_lds[t*17 + b] = x[(size_t)(b0+b)*TT + t];
    }
    for (int i = tid; i < (int)sizeof(hraw)/4; i += 896)
        ((unsigned int*)hraw)[i] = 0u;
    if (tid < 64) ((float*)s_fc)[tid] = 0.f;

    // ---- persistent weights ----
    f16x8 wI[4][2], wH[4][2];
    float bcr[16], wih1r[16];
    if (role < 3){
        const float* Wih = (role == 1) ? w_ih2 : w_ih3;
        const float* Whh = (role == 0) ? w_hh1 : (role == 1 ? w_hh2 : w_hh3);
        const float* bp  = (role == 0) ? b1   : (role == 1 ? b2    : b3);
        #pragma unroll
        for (int g = 0; g < 4; ++g){
            const float sg = (g == 2) ? LOG2E2 : LOG2E;
            const int row = g*64 + uq*16 + bb;
            #pragma unroll
            for (int kh = 0; kh < 2; ++kh){
                wH[g][kh] = ldw8s(Whh + row*64 + kh*32 + q*8, sg);
                if (role != 0) wI[g][kh] = ldw8s(Wih + row*64 + kh*32 + q*8, sg);
            }
            #pragma unroll
            for (int j = 0; j < 4; ++j){
                const int rj = g*64 + uq*16 + 4*q + j;
                bcr[g*4+j] = bp[rj]*sg;
                if (role == 0) wih1r[g*4+j] = w_ih1[rj]*sg;
            }
        }
    }

    // FC fragments (waves 12,13; tile ti = wid-12)
    f16x8 wfc[2];
    float fc1br[4], fc2wr[4];
    const float fc2bs = fc2_b[0];
    if (role == 3){
        const int ti = wid - 12;
        #pragma unroll
        for (int kh = 0; kh < 2; ++kh)
            wfc[kh] = ldw8s(fc1_w + (ti*16 + bb)*64 + kh*32 + q*8, 1.0f);
        #pragma unroll
        for (int j = 0; j < 4; ++j){
            fc1br[j] = fc1_b[ti*16 + 4*q + j];
            fc2wr[j] = fc2_w[ti*16 + 4*q + j];
        }
    }

    float c[4] = {0.f, 0.f, 0.f, 0.f};
    float obuf0 = 0.f, obuf1 = 0.f, obuf2 = 0.f;

    // t-invariant LDS byte offsets (R1-verified swizzle)
    const int rowb = bb*128;
    const int swz  = 16*(bb&7);
    const int rdA  = rowb + ((16*q     ) ^ swz);
    const int rdB  = rowb + ((16*q + 64) ^ swz);
    const int wro  = rowb + ((uq*32 + 8*q) ^ swz);

    __syncthreads();

    #pragma unroll 1
    for (int p = 0; p < TT + 4; ++p){
        if (role == 0){
            const int t = p;
            if (t < TT){
                const unsigned char* hr = hraw + (((t-1)&1) << 11);
                unsigned char*       hw = hraw + (((t  )&1) << 11);
                const f16x8 hA = *(const f16x8*)(hr + rdA);
                const f16x8 hB = *(const f16x8*)(hr + rdB);
                const float xv = x_lds[t*17 + bb];
                f32x4 a0, a1, a2, a3;
                #pragma unroll
                for (int j = 0; j < 4; ++j){
                    a0[j] = fmaf(wih1r[j],    xv, bcr[j]);
                    a1[j] = fmaf(wih1r[4+j],  xv, bcr[4+j]);
                    a2[j] = fmaf(wih1r[8+j],  xv, bcr[8+j]);
                    a3[j] = fmaf(wih1r[12+j], xv, bcr[12+j]);
                }
                a0 = MFMA(wH[0][0], hA, a0); a1 = MFMA(wH[1][0], hA, a1);
                a2 = MFMA(wH[2][0], hA, a2); a3 = MFMA(wH[3][0], hA, a3);
                a0 = MFMA(wH[0][1], hB, a0); a1 = MFMA(wH[1][1], hB, a1);
                a2 = MFMA(wH[2][1], hB, a2); a3 = MFMA(wH[3][1], hB, a3);
                f16x4 hn;
                act4(a0, a1, a2, a3, c, hn);
                *(f16x4*)(hw + wro) = hn;
            }
        } else if (role < 3){
            const int t = (role == 1) ? (p - 1) : (p - 2);
            if (t >= 0 && t < TT){
                const int inL = role - 1;
                const int myL = role;
                const unsigned char* ir = hraw + inL*4096 + (((t  )&1) << 11);
                const unsigned char* hr = hraw + myL*4096 + (((t-1)&1) << 11);
                unsigned char*       hw = hraw + myL*4096 + (((t  )&1) << 11);
                const f16x8 iA = *(const f16x8*)(ir + rdA);
                const f16x8 iB = *(const f16x8*)(ir + rdB);
                const f16x8 hA = *(const f16x8*)(hr + rdA);
                const f16x8 hB = *(const f16x8*)(hr + rdB);
                f32x4 a0, a1, a2, a3;
                #pragma unroll
                for (int j = 0; j < 4; ++j){
                    a0[j] = bcr[j]; a1[j] = bcr[4+j]; a2[j] = bcr[8+j]; a3[j] = bcr[12+j];
                }
                a0 = MFMA(wI[0][0], iA, a0); a1 = MFMA(wI[1][0], iA, a1);
                a2 = MFMA(wI[2][0], iA, a2); a3 = MFMA(wI[3][0], iA, a3);
                a0 = MFMA(wI[0][1], iB, a0); a1 = MFMA(wI[1][1], iB, a1);
                a2 = MFMA(wI[2][1], iB, a2); a3 = MFMA(wI[3][1], iB, a3);
                a0 = MFMA(wH[0][0], hA, a0); a1 = MFMA(wH[1][0], hA, a1);
                a2 = MFMA(wH[2][0], hA, a2); a3 = MFMA(wH[3][0], hA, a3);
                a0 = MFMA(wH[0][1], hB, a0); a1 = MFMA(wH[1][1], hB, a1);
                a2 = MFMA(wH[2][1], hB, a2); a3 = MFMA(wH[3][1], hB, a3);
                f16x4 hn;
                act4(a0, a1, a2, a3, c, hn);
                *(f16x4*)(hw + wro) = hn;
            }
        } else {
            const int ti = wid - 12;
            const int tf = p - 3;
            if (tf >= 0 && tf < TT){
                const unsigned char* h3r = hraw + 2*4096 + ((tf&1) << 11);
                const f16x8 pA = *(const f16x8*)(h3r + rdA);
                const f16x8 pB = *(const f16x8*)(h3r + rdB);
                f32x4 y;
                #pragma unroll
                for (int j = 0; j < 4; ++j) y[j] = fc1br[j];
                y = MFMA(wfc[0], pA, y);
                y = MFMA(wfc[1], pB, y);
                float s = 0.f;
                #pragma unroll
                for (int j = 0; j < 4; ++j){
                    float u = fmaxf(y[j], 0.2f*y[j]);       // leaky_relu(0.2)
                    s = fmaf(u, fc2wr[j], s);
                }
                s += __shfl_xor(s, 16);
                s += __shfl_xor(s, 32);
                if (l < 16) s_fc[ti][tf&1][l] = s;
            }
            const int to = p - 4;
            if (ti == 0 && to >= 0 && l < 16){
                float s = s_fc[0][to&1][l] + s_fc[1][to&1][l] + fc2bs;
                const int ph = to & 3;
                if (ph == 0) obuf0 = s;
                else if (ph == 1) obuf1 = s;
                else if (ph == 2) obuf2 = s;
                else {
                    float4 v = make_float4(obuf0, obuf1, obuf2, s);
                    *(float4*)(out + (size_t)(b0+l)*TT + (to - 3)) = v;
                }
            }
        }
        __syncthreads();
    }
}

extern "C" void kernel_launch(void* const* d_in, const int* in_sizes, int n_in,
                              void* d_out, int out_size, void* d_ws, size_t ws_size,
                              hipStream_t stream)
{
    (void)in_sizes; (void)n_in; (void)d_ws; (void)ws_size; (void)out_size;
    const float* x     = (const float*)d_in[0];
    const float* w_ih1 = (const float*)d_in[1];
    const float* w_hh1 = (const float*)d_in[2];
    const float* b1    = (const float*)d_in[3];
    const float* w_ih2 = (const float*)d_in[4];
    const float* w_hh2 = (const float*)d_in[5];
    const float* b2    = (const float*)d_in[6];
    const float* w_ih3 = (const float*)d_in[7];
    const float* w_hh3 = (const float*)d_in[8];
    const float* b3    = (const float*)d_in[9];
    const float* fc1_w = (const float*)d_in[10];
    const float* fc1_b = (const float*)d_in[11];
    const float* fc2_w = (const float*)d_in[12];
    const float* fc2_b = (const float*)d_in[13];

    lstm3_pipe2<<<dim3(64), dim3(896), 0, stream>>>(
        x, w_ih1, w_hh1, b1, w_ih2, w_hh2, b2, w_ih3, w_hh3, b3,
        fc1_w, fc1_b, fc2_w, fc2_b, (float*)d_out);
}

// Round 5
// 521.757 us; speedup vs baseline: 2.4010x; 2.4010x over previous
//
#include <hip/hip_runtime.h>

#define TT 512

typedef _Float16 f16;
typedef _Float16 f16x4 __attribute__((ext_vector_type(4)));
typedef _Float16 f16x8 __attribute__((ext_vector_type(8)));
typedef float    f32x4 __attribute__((ext_vector_type(4)));

#define MFMA(A, B, C) __builtin_amdgcn_mfma_f32_16x16x32_f16((A), (B), (C), 0, 0, 0)

#define LOG2E  1.44269504f
#define LOG2E2 2.88539008f

__device__ __forceinline__ float exp2_(float x){
#if __has_builtin(__builtin_amdgcn_exp2f)
    return __builtin_amdgcn_exp2f(x);
#else
    return exp2f(x);
#endif
}
__device__ __forceinline__ float rcp_(float x){
#if __has_builtin(__builtin_amdgcn_rcpf)
    return __builtin_amdgcn_rcpf(x);
#else
    return 1.0f/x;
#endif
}
__device__ __forceinline__ f16x8 ldw8s(const float* p, float s){
    f16x8 r;
    #pragma unroll
    for (int i = 0; i < 8; ++i) r[i] = (f16)(p[i]*s);
    return r;
}

// Gate pre-scaling: i/f/o rows by LOG2E, g rows by LOG2E2 (folded into W+b).
// Shared-rcp: sig(a)*tanh(b) = (1-Eb)/((1+Ea)(1+Eb)) -> 8 trans/(unit,batch).
__device__ __forceinline__ void act4(const f32x4& zi, const f32x4& zf,
                                     const f32x4& zg, const f32x4& zo,
                                     float* c, f16x4& hn){
    #pragma unroll
    for (int j = 0; j < 4; ++j){
        float Ei = exp2_(-zi[j]);
        float Ef = exp2_(-zf[j]);
        float Eg = exp2_(-zg[j]);
        float Eo = exp2_(-zo[j]);
        float ig = (1.0f - Eg) * rcp_((1.0f + Ei)*(1.0f + Eg));   // i*g
        float f_ = rcp_(1.0f + Ef);                                // f
        c[j] = fmaf(f_, c[j], ig);
        float Ec = exp2_(-(LOG2E2*c[j]));
        float h_ = (1.0f - Ec) * rcp_((1.0f + Eo)*(1.0f + Ec));   // o*tanh(c)
        hn[j] = (f16)h_;
    }
}

// 64 blocks x 768 threads (12 waves) — R2-proven shell (VGPR~80, no scratch).
//   phase p:  waves 0-3: L1 @ t=p   waves 4-7: L2 @ t=p-1   waves 8-11: L3 @ t=p-2
//             waves 0,1 also: FC tile 0/1 @ t=p-3; wave 1 stores out @ t=p-4
// One __syncthreads per phase; NO global loads in the loop (x pre-staged in LDS);
// out stores batched x4 (float4) so store-drain hits 1 phase in 4.
__global__ __launch_bounds__(768, 1) void lstm3_pipe3(
    const float* __restrict__ x,
    const float* __restrict__ w_ih1, const float* __restrict__ w_hh1, const float* __restrict__ b1,
    const float* __restrict__ w_ih2, const float* __restrict__ w_hh2, const float* __restrict__ b2,
    const float* __restrict__ w_ih3, const float* __restrict__ w_hh3, const float* __restrict__ b3,
    const float* __restrict__ fc1_w, const float* __restrict__ fc1_b,
    const float* __restrict__ fc2_w, const float* __restrict__ fc2_b,
    float* __restrict__ out)
{
    __shared__ __align__(16) unsigned char hraw[3*2*2048];  // [layer][parity][16b][64u] f16 swizzled
    __shared__ float x_lds[TT*17];                          // [t][batch], stride 17
    __shared__ float s_fc[2][2][16];                        // [fc tile][parity][batch]

    const int tid = threadIdx.x;
    const int wid = tid >> 6;
    const int l   = tid & 63;
    const int q   = l >> 4;
    const int bb  = l & 15;
    const int b0  = blockIdx.x * 16;
    const int role = (wid < 4) ? 0 : (wid < 8 ? 1 : 2);
    const int uq   = wid & 3;

    // stage x transposed: coalesced global read; stride-17 write is bank-clean
    for (int i = tid; i < 16*TT; i += 768){
        int b = i >> 9, t = i & (TT-1);
        x_lds[t*17 + b] = x[(size_t)(b0+b)*TT + t];
    }
    for (int i = tid; i < (int)sizeof(hraw)/4; i += 768)
        ((unsigned int*)hraw)[i] = 0u;
    if (tid < 64) ((float*)s_fc)[tid] = 0.f;

    // ---- persistent weights (identical structure to R2: VGPR-feasible) ----
    const float* Wih = (role == 1) ? w_ih2 : w_ih3;
    const float* Whh = (role == 0) ? w_hh1 : (role == 1 ? w_hh2 : w_hh3);
    const float* bp  = (role == 0) ? b1   : (role == 1 ? b2    : b3);

    f16x8 wI[4][2], wH[4][2];
    float bcr[16], wih1r[16];
    #pragma unroll
    for (int g = 0; g < 4; ++g){
        const float sg = (g == 2) ? LOG2E2 : LOG2E;
        const int row = g*64 + uq*16 + bb;
        #pragma unroll
        for (int kh = 0; kh < 2; ++kh){
            wH[g][kh] = ldw8s(Whh + row*64 + kh*32 + q*8, sg);
            if (role != 0) wI[g][kh] = ldw8s(Wih + row*64 + kh*32 + q*8, sg);
        }
        #pragma unroll
        for (int j = 0; j < 4; ++j){
            const int rj = g*64 + uq*16 + 4*q + j;
            bcr[g*4+j] = bp[rj]*sg;
            if (role == 0) wih1r[g*4+j] = w_ih1[rj]*sg;
        }
    }

    // FC fragments (waves 0,1 only; tile ti = wid)
    f16x8 wfc[2];
    float fc1br[4], fc2wr[4];
    const float fc2bs = fc2_b[0];
    if (wid < 2){
        #pragma unroll
        for (int kh = 0; kh < 2; ++kh)
            wfc[kh] = ldw8s(fc1_w + (wid*16 + bb)*64 + kh*32 + q*8, 1.0f);
        #pragma unroll
        for (int j = 0; j < 4; ++j){
            fc1br[j] = fc1_b[wid*16 + 4*q + j];
            fc2wr[j] = fc2_w[wid*16 + 4*q + j];
        }
    }

    float c[4] = {0.f, 0.f, 0.f, 0.f};
    float obuf0 = 0.f, obuf1 = 0.f, obuf2 = 0.f;

    // t-invariant LDS byte offsets (R1-verified swizzle)
    const int rowb = bb*128;
    const int swz  = 16*(bb&7);
    const int rdA  = rowb + ((16*q     ) ^ swz);
    const int rdB  = rowb + ((16*q + 64) ^ swz);
    const int wro  = rowb + ((uq*32 + 8*q) ^ swz);

    __syncthreads();

    #pragma unroll 1
    for (int p = 0; p < TT + 4; ++p){
        if (role == 0){
            const int t = p;
            if (t < TT){
                const unsigned char* hr = hraw + (((t-1)&1) << 11);
                unsigned char*       hw = hraw + (((t  )&1) << 11);
                const f16x8 hA = *(const f16x8*)(hr + rdA);
                const f16x8 hB = *(const f16x8*)(hr + rdB);
                const float xv = x_lds[t*17 + bb];
                f32x4 a0, a1, a2, a3;
                #pragma unroll
                for (int j = 0; j < 4; ++j){
                    a0[j] = fmaf(wih1r[j],    xv, bcr[j]);
                    a1[j] = fmaf(wih1r[4+j],  xv, bcr[4+j]);
                    a2[j] = fmaf(wih1r[8+j],  xv, bcr[8+j]);
                    a3[j] = fmaf(wih1r[12+j], xv, bcr[12+j]);
                }
                a0 = MFMA(wH[0][0], hA, a0); a1 = MFMA(wH[1][0], hA, a1);
                a2 = MFMA(wH[2][0], hA, a2); a3 = MFMA(wH[3][0], hA, a3);
                a0 = MFMA(wH[0][1], hB, a0); a1 = MFMA(wH[1][1], hB, a1);
                a2 = MFMA(wH[2][1], hB, a2); a3 = MFMA(wH[3][1], hB, a3);
                f16x4 hn;
                act4(a0, a1, a2, a3, c, hn);
                *(f16x4*)(hw + wro) = hn;
            }
            if (wid < 2){
                const int tf = p - 3;
                if (tf >= 0 && tf < TT){
                    const unsigned char* h3r = hraw + 2*4096 + ((tf&1) << 11);
                    const f16x8 pA = *(const f16x8*)(h3r + rdA);
                    const f16x8 pB = *(const f16x8*)(h3r + rdB);
                    f32x4 y;
                    #pragma unroll
                    for (int j = 0; j < 4; ++j) y[j] = fc1br[j];
                    y = MFMA(wfc[0], pA, y);
                    y = MFMA(wfc[1], pB, y);
                    float s = 0.f;
                    #pragma unroll
                    for (int j = 0; j < 4; ++j){
                        float u = fmaxf(y[j], 0.2f*y[j]);   // leaky_relu(0.2)
                        s = fmaf(u, fc2wr[j], s);
                    }
                    s += __shfl_xor(s, 16);
                    s += __shfl_xor(s, 32);
                    if (l < 16) s_fc[wid][tf&1][l] = s;
                }
                const int to = p - 4;
                if (wid == 1 && to >= 0 && l < 16){
                    float s = s_fc[0][to&1][l] + s_fc[1][to&1][l] + fc2bs;
                    const int ph = to & 3;
                    if (ph == 0) obuf0 = s;
                    else if (ph == 1) obuf1 = s;
                    else if (ph == 2) obuf2 = s;
                    else {
                        float4 v = make_float4(obuf0, obuf1, obuf2, s);
                        *(float4*)(out + (size_t)(b0+l)*TT + (to - 3)) = v;
                    }
                }
            }
        } else {
            const int t = (role == 1) ? (p - 1) : (p - 2);
            if (t >= 0 && t < TT){
                const int inL  = role - 1;
                const int myL  = role;
                const unsigned char* ir = hraw + inL*4096 + (((t  )&1) << 11);
                const unsigned char* hr = hraw + myL*4096 + (((t-1)&1) << 11);
                unsigned char*       hw = hraw + myL*4096 + (((t  )&1) << 11);
                const f16x8 iA = *(const f16x8*)(ir + rdA);
                const f16x8 iB = *(const f16x8*)(ir + rdB);
                const f16x8 hA = *(const f16x8*)(hr + rdA);
                const f16x8 hB = *(const f16x8*)(hr + rdB);
                f32x4 a0, a1, a2, a3;
                #pragma unroll
                for (int j = 0; j < 4; ++j){
                    a0[j] = bcr[j]; a1[j] = bcr[4+j]; a2[j] = bcr[8+j]; a3[j] = bcr[12+j];
                }
                a0 = MFMA(wI[0][0], iA, a0); a1 = MFMA(wI[1][0], iA, a1);
                a2 = MFMA(wI[2][0], iA, a2); a3 = MFMA(wI[3][0], iA, a3);
                a0 = MFMA(wI[0][1], iB, a0); a1 = MFMA(wI[1][1], iB, a1);
                a2 = MFMA(wI[2][1], iB, a2); a3 = MFMA(wI[3][1], iB, a3);
                a0 = MFMA(wH[0][0], hA, a0); a1 = MFMA(wH[1][0], hA, a1);
                a2 = MFMA(wH[2][0], hA, a2); a3 = MFMA(wH[3][0], hA, a3);
                a0 = MFMA(wH[0][1], hB, a0); a1 = MFMA(wH[1][1], hB, a1);
                a2 = MFMA(wH[2][1], hB, a2); a3 = MFMA(wH[3][1], hB, a3);
                f16x4 hn;
                act4(a0, a1, a2, a3, c, hn);
                *(f16x4*)(hw + wro) = hn;
            }
        }
        __syncthreads();
    }
}

extern "C" void kernel_launch(void* const* d_in, const int* in_sizes, int n_in,
                              void* d_out, int out_size, void* d_ws, size_t ws_size,
                              hipStream_t stream)
{
    (void)in_sizes; (void)n_in; (void)d_ws; (void)ws_size; (void)out_size;
    const float* x     = (const float*)d_in[0];
    const float* w_ih1 = (const float*)d_in[1];
    const float* w_hh1 = (const float*)d_in[2];
    const float* b1    = (const float*)d_in[3];
    const float* w_ih2 = (const float*)d_in[4];
    const float* w_hh2 = (const float*)d_in[5];
    const float* b2    = (const float*)d_in[6];
    const float* w_ih3 = (const float*)d_in[7];
    const float* w_hh3 = (const float*)d_in[8];
    const float* b3    = (const float*)d_in[9];
    const float* fc1_w = (const float*)d_in[10];
    const float* fc1_b = (const float*)d_in[11];
    const float* fc2_w = (const float*)d_in[12];
    const float* fc2_b = (const float*)d_in[13];

    lstm3_pipe3<<<dim3(64), dim3(768), 0, stream>>>(
        x, w_ih1, w_hh1, b1, w_ih2, w_hh2, b2, w_ih3, w_hh3, b3,
        fc1_w, fc1_b, fc2_w, fc2_b, (float*)d_out);
}